// Round 7
// baseline (720.501 us; speedup 1.0000x reference)
//
#include <hip/hip_runtime.h>
#include <stdint.h>

#define T_LEN 2048
#define B_TOT 64
#define N_TAG 128
#define MID 1024  // fwd applies M_1..M_{MID-1}; bwd applies M'_{MID}..M'_{T-1}

typedef __attribute__((ext_vector_type(4))) float f32x4;
typedef __attribute__((ext_vector_type(8))) short bf16x8;
typedef __attribute__((ext_vector_type(4))) uint32_t u32x4;

template <int S>
struct IC {
  static constexpr int value = S;
};

// boundary handoff (written by chain blocks, combined by the last block to
// finish via device-scope ticket; __threadfence gives cross-XCD visibility)
__device__ __align__(16) float g_alpha[B_TOT][N_TAG];
__device__ __align__(16) float g_v[B_TOT][N_TAG];
__device__ float g_Lf[B_TOT];
__device__ float g_Lb[B_TOT];
__device__ int g_done = 0;

// pack two fp32 -> dword of two bf16 (round-half-up); elem0 in low half
__device__ __forceinline__ uint32_t pack2_bf16(float a, float b) {
  uint32_t ua = __float_as_uint(a) + 0x8000u;
  uint32_t ub = __float_as_uint(b) + 0x8000u;
  return __builtin_amdgcn_perm(ua, ub, 0x03020706u);
}
__device__ __forceinline__ float bf_lo(uint32_t w) {
  return __uint_as_float(w << 16);
}
__device__ __forceinline__ float bf_hi(uint32_t w) {
  return __uint_as_float(w & 0xffff0000u);
}

// prepass: ws[t][b][i] = bf16(exp(em[b][t][i])), i-pairs packed in u32.
// Separate launch (R4: fusing this traffic into the scan poisons the
// latency-critical loop); stream order guarantees visibility to the scan.
__global__ __launch_bounds__(256) void eem_prepass(const float* __restrict__ em,
                                                   uint32_t* __restrict__ ws) {
  const int tid = blockIdx.x * blockDim.x + threadIdx.x;  // 0 .. 2^21-1
  const int b = tid >> 15;
  const int rem = tid & 32767;
  const int t = rem >> 4;
  const int kk = rem & 15;  // 8 floats per thread
  const float4* src =
      (const float4*)(em + ((size_t)b * T_LEN + t) * N_TAG + kk * 8);
  const float4 p0 = src[0];
  const float4 p1 = src[1];
  u32x4 o;
  o[0] = pack2_bf16(__expf(p0.x), __expf(p0.y));
  o[1] = pack2_bf16(__expf(p0.z), __expf(p0.w));
  o[2] = pack2_bf16(__expf(p1.x), __expf(p1.y));
  o[3] = pack2_bf16(__expf(p1.z), __expf(p1.w));
  *(u32x4*)(ws + ((size_t)t * B_TOT + b) * (N_TAG / 2) + kk * 4) = o;
}

// R6: one wave = one whole chain. 8 blocks x 64 threads:
//   blocks 0-3: fwd chains (batch groups 0-3), t = 1..1023 (maskless,
//               len >= 1024); blocks 4-7: bwd chains, t = 2047..1024 with
//               per-lane identity select for t >= len.
// The wave holds the FULL 16-batch state in 4 packed B-fragments (16 VGPRs)
// and the full exp(trans) as 32 A-fragments (128 VGPRs), computing all 8
// output tiles (32 MFMAs, 8 independent 4-chains) per step. A-row
// permutation per (f,h) tile makes the 8 D outputs land register-local as
// exactly the next step's 4 B-fragments: NO LDS, NO barriers, NO cross-lane
// traffic in the loop (R5 lesson: the LDS exchange was the ~400 cyc/step
// wall; R1 lesson: its 2-wave/SIMD hiding was load-bearing -- here ILP from
// 8 independent chains replaces it). Rescale probe via __shfl broadcast.
// eem through a 4-slot x 4-fragment prefetch ring (L2/L3-resident table).
__global__ __launch_bounds__(64, 1) void crf_chain_kernel(
    const float* __restrict__ em, const int* __restrict__ lens,
    const float* __restrict__ trans, const float* __restrict__ head,
    const float* __restrict__ last, const uint32_t* __restrict__ eem,
    float* __restrict__ out) {
  const int lane = threadIdx.x;  // 0..63
  const int c = lane & 15;       // batch-in-group
  const int q = lane >> 4;       // 0..3
  const bool is_fwd = (blockIdx.x < 4);
  const int bg = ((int)blockIdx.x & 3) * 16 + c;

  const uint32_t* eqp = eem + (size_t)bg * 64 + q * 4;
  const float* emb = em + (size_t)bg * T_LEN * N_TAG;

  u32x4 eslot[16];        // [slot][frag]
  bf16x8 efrag[4][2][4];  // [frag][half][ktile]
  u32x4 xfrag[4];         // packed state: frag f = j/i = f*32+q*8+0..7
  float L = 0.f;
  int kb = 0;
  const f32x4 vzero = {0.f, 0.f, 0.f, 0.f};

  if (is_fwd) {
    // ============ forward chain: alpha_{t} for t = 1..1023 ============
    // A tile (f,h): row m=c -> j = f*32 + (c>>2)*8 + h*4 + (c&3), k = i
#pragma unroll
    for (int f = 0; f < 4; ++f) {
#pragma unroll
      for (int h = 0; h < 2; ++h) {
        const int j = f * 32 + (c >> 2) * 8 + h * 4 + (c & 3);
#pragma unroll
        for (int kt = 0; kt < 4; ++kt) {
          u32x4 wd;
#pragma unroll
          for (int p = 0; p < 4; ++p) {
            const int i0 = kt * 32 + q * 8 + 2 * p;
            wd[p] = pack2_bf16(__expf(trans[(i0 + 0) * N_TAG + j]),
                               __expf(trans[(i0 + 1) * N_TAG + j]));
          }
          efrag[f][h][kt] = __builtin_bit_cast(bf16x8, wd);
        }
      }
    }
    // alpha_0 = exp(head + em[0])
#pragma unroll
    for (int f = 0; f < 4; ++f) {
      const int jf = f * 32 + q * 8;
      float v0[8];
#pragma unroll
      for (int r = 0; r < 8; ++r) v0[r] = __expf(head[jf + r] + emb[jf + r]);
      u32x4 wd;
#pragma unroll
      for (int d = 0; d < 4; ++d)
        wd[d] = pack2_bf16(v0[2 * d], v0[2 * d + 1]);
      xfrag[f] = wd;
    }
    // ring init: slot S holds row S (S = 1..3)
#pragma unroll
    for (int S = 1; S < 4; ++S)
#pragma unroll
      for (int f = 0; f < 4; ++f)
        eslot[S * 4 + f] = *(const u32x4*)(eqp + (size_t)S * 4096 + f * 16);

    auto stepf = [&](auto sc_, int t) {
      constexpr int SLOT = decltype(sc_)::value;
      {  // refill slot freed last step: row t+3 (max 1026 < 2048)
        const uint32_t* rp = eqp + (size_t)(t + 3) * 4096;
#pragma unroll
        for (int f = 0; f < 4; ++f)
          eslot[((SLOT + 3) & 3) * 4 + f] = *(const u32x4*)(rp + f * 16);
      }
      // 8 tiles as 8 independent 4-deep MFMA chains
      f32x4 acc[4][2];
#pragma unroll
      for (int f = 0; f < 4; ++f) {
#pragma unroll
        for (int h = 0; h < 2; ++h) {
          f32x4 a = __builtin_amdgcn_mfma_f32_16x16x32_bf16(
              efrag[f][h][0], __builtin_bit_cast(bf16x8, xfrag[0]), vzero, 0,
              0, 0);
          a = __builtin_amdgcn_mfma_f32_16x16x32_bf16(
              efrag[f][h][1], __builtin_bit_cast(bf16x8, xfrag[1]), a, 0, 0,
              0);
          a = __builtin_amdgcn_mfma_f32_16x16x32_bf16(
              efrag[f][h][2], __builtin_bit_cast(bf16x8, xfrag[2]), a, 0, 0,
              0);
          a = __builtin_amdgcn_mfma_f32_16x16x32_bf16(
              efrag[f][h][3], __builtin_bit_cast(bf16x8, xfrag[3]), a, 0, 0,
              0);
          acc[f][h] = a;
        }
      }
      float ff[4][8];
#pragma unroll
      for (int f = 0; f < 4; ++f) {
        const u32x4 ev = eslot[SLOT * 4 + f];
#pragma unroll
        for (int d = 0; d < 4; ++d) {
          ff[f][2 * d] = bf_lo(ev[d]);
          ff[f][2 * d + 1] = bf_hi(ev[d]);
        }
      }
      if (SLOT == 1) {  // apply rescale probed 1 step earlier
        const float sc = __uint_as_float((uint32_t)(127 - kb) << 23);
#pragma unroll
        for (int f = 0; f < 4; ++f)
#pragma unroll
          for (int r = 0; r < 8; ++r) ff[f][r] *= sc;
        L += (float)kb * 0.6931471805599453f;
      }
      if (SLOT == 0) {  // exponent probe of alpha[j=0][c] (lane (c,0))
        const int kr = (int)(__float_as_uint(acc[0][0][0]) >> 23) - 126;
        kb = __shfl(kr, c, 64);
      }
#pragma unroll
      for (int f = 0; f < 4; ++f) {
        u32x4 wd;
        wd[0] = pack2_bf16(acc[f][0][0] * ff[f][0], acc[f][0][1] * ff[f][1]);
        wd[1] = pack2_bf16(acc[f][0][2] * ff[f][2], acc[f][0][3] * ff[f][3]);
        wd[2] = pack2_bf16(acc[f][1][0] * ff[f][4], acc[f][1][1] * ff[f][5]);
        wd[3] = pack2_bf16(acc[f][1][2] * ff[f][6], acc[f][1][3] * ff[f][7]);
        xfrag[f] = wd;
      }
    };

    int t = 1;
#pragma unroll 1
    for (int it = 0; it < 255; ++it) {  // t = 1 .. 1020
      stepf(IC<1>{}, t);
      stepf(IC<2>{}, t + 1);
      stepf(IC<3>{}, t + 2);
      stepf(IC<0>{}, t + 3);
      t += 4;
    }
    stepf(IC<1>{}, t);      // 1021
    stepf(IC<2>{}, t + 1);  // 1022
    stepf(IC<3>{}, t + 2);  // 1023
    // capture alpha_{MID-1} (bf16 state -- same precision as the chain)
#pragma unroll
    for (int f = 0; f < 4; ++f) {
      const int jf = f * 32 + q * 8;
#pragma unroll
      for (int d = 0; d < 4; ++d) {
        g_alpha[bg][jf + 2 * d] = bf_lo(xfrag[f][d]);
        g_alpha[bg][jf + 2 * d + 1] = bf_hi(xfrag[f][d]);
      }
    }
    if (lane < 16) g_Lf[bg] = L;
  } else {
    // ============ backward chain: v_t for t = 2047..1024 ============
    // A tile (f,h): row m=c -> i = f*32 + (c>>2)*8 + h*4 + (c&3), k = j'
#pragma unroll
    for (int f = 0; f < 4; ++f) {
#pragma unroll
      for (int h = 0; h < 2; ++h) {
        const int irow = f * 32 + (c >> 2) * 8 + h * 4 + (c & 3);
#pragma unroll
        for (int kt = 0; kt < 4; ++kt) {
          u32x4 wd;
#pragma unroll
          for (int p = 0; p < 4; ++p) {
            const int j0 = kt * 32 + q * 8 + 2 * p;
            wd[p] = pack2_bf16(__expf(trans[irow * N_TAG + j0 + 0]),
                               __expf(trans[irow * N_TAG + j0 + 1]));
          }
          efrag[f][h][kt] = __builtin_bit_cast(bf16x8, wd);
        }
      }
    }
    const int mylen = lens[bg];
    f32x4 vcur[4][2];  // v state in f32 (pre-emission), tile layout
#pragma unroll
    for (int f = 0; f < 4; ++f)
#pragma unroll
      for (int h = 0; h < 2; ++h) {
        const int ib = f * 32 + q * 8 + h * 4;
#pragma unroll
        for (int r = 0; r < 4; ++r) vcur[f][h][r] = __expf(last[ib + r]);
      }
    // xfrag = u_{2047} = e_{2047} (*) v_2048
#pragma unroll
    for (int f = 0; f < 4; ++f) {
      const int jf = f * 32 + q * 8;
      float e0[8];
#pragma unroll
      for (int r = 0; r < 8; ++r)
        e0[r] = __expf(emb[(size_t)(T_LEN - 1) * N_TAG + jf + r]);
      u32x4 wd;
      wd[0] = pack2_bf16(vcur[f][0][0] * e0[0], vcur[f][0][1] * e0[1]);
      wd[1] = pack2_bf16(vcur[f][0][2] * e0[2], vcur[f][0][3] * e0[3]);
      wd[2] = pack2_bf16(vcur[f][1][0] * e0[4], vcur[f][1][1] * e0[5]);
      wd[3] = pack2_bf16(vcur[f][1][2] * e0[6], vcur[f][1][3] * e0[7]);
      xfrag[f] = wd;
    }
    // ring init: slot S holds row 2047-S (e_{t-1} for step t = 2048-S)
#pragma unroll
    for (int S = 1; S < 4; ++S)
#pragma unroll
      for (int f = 0; f < 4; ++f)
        eslot[S * 4 + f] =
            *(const u32x4*)(eqp + (size_t)(T_LEN - 1 - S) * 4096 + f * 16);

    auto stepb = [&](auto sc_, int t) {
      constexpr int SLOT = decltype(sc_)::value;
      {  // refill: row t-4 (min 1020 >= 0)
        const uint32_t* rp = eqp + (size_t)(t - 4) * 4096;
#pragma unroll
        for (int f = 0; f < 4; ++f)
          eslot[((SLOT + 3) & 3) * 4 + f] = *(const u32x4*)(rp + f * 16);
      }
      f32x4 acc[4][2];
#pragma unroll
      for (int f = 0; f < 4; ++f) {
#pragma unroll
        for (int h = 0; h < 2; ++h) {
          f32x4 a = __builtin_amdgcn_mfma_f32_16x16x32_bf16(
              efrag[f][h][0], __builtin_bit_cast(bf16x8, xfrag[0]), vzero, 0,
              0, 0);
          a = __builtin_amdgcn_mfma_f32_16x16x32_bf16(
              efrag[f][h][1], __builtin_bit_cast(bf16x8, xfrag[1]), a, 0, 0,
              0);
          a = __builtin_amdgcn_mfma_f32_16x16x32_bf16(
              efrag[f][h][2], __builtin_bit_cast(bf16x8, xfrag[2]), a, 0, 0,
              0);
          a = __builtin_amdgcn_mfma_f32_16x16x32_bf16(
              efrag[f][h][3], __builtin_bit_cast(bf16x8, xfrag[3]), a, 0, 0,
              0);
          acc[f][h] = a;
        }
      }
      float ee[4][8];
#pragma unroll
      for (int f = 0; f < 4; ++f) {
        const u32x4 ev = eslot[SLOT * 4 + f];
#pragma unroll
        for (int d = 0; d < 4; ++d) {
          ee[f][2 * d] = bf_lo(ev[d]);
          ee[f][2 * d + 1] = bf_hi(ev[d]);
        }
      }
      // identity select for padded steps (t >= len): keep v unchanged
      const bool valid = (t < mylen);
#pragma unroll
      for (int f = 0; f < 4; ++f)
#pragma unroll
        for (int h = 0; h < 2; ++h)
          vcur[f][h] = valid ? acc[f][h] : vcur[f][h];
      if (SLOT == 1) {
        const float sc = __uint_as_float((uint32_t)(127 - kb) << 23);
#pragma unroll
        for (int f = 0; f < 4; ++f)
#pragma unroll
          for (int h = 0; h < 2; ++h)
#pragma unroll
            for (int r = 0; r < 4; ++r) vcur[f][h][r] *= sc;
        L += (float)kb * 0.6931471805599453f;
      }
      if (SLOT == 0) {
        const int kr = (int)(__float_as_uint(vcur[0][0][0]) >> 23) - 126;
        kb = __shfl(kr, c, 64);
      }
#pragma unroll
      for (int f = 0; f < 4; ++f) {
        u32x4 wd;
        wd[0] = pack2_bf16(vcur[f][0][0] * ee[f][0], vcur[f][0][1] * ee[f][1]);
        wd[1] = pack2_bf16(vcur[f][0][2] * ee[f][2], vcur[f][0][3] * ee[f][3]);
        wd[2] = pack2_bf16(vcur[f][1][0] * ee[f][4], vcur[f][1][1] * ee[f][5]);
        wd[3] = pack2_bf16(vcur[f][1][2] * ee[f][6], vcur[f][1][3] * ee[f][7]);
        xfrag[f] = wd;
      }
    };

    int t = T_LEN - 1;  // 2047
#pragma unroll 1
    for (int it = 0; it < 256; ++it) {  // t = 2047 .. 1024
      stepb(IC<1>{}, t);
      stepb(IC<2>{}, t - 1);
      stepb(IC<3>{}, t - 2);
      stepb(IC<0>{}, t - 3);
      t -= 4;
    }
    // capture v_MID (f32, pre-emission)
#pragma unroll
    for (int f = 0; f < 4; ++f)
#pragma unroll
      for (int h = 0; h < 2; ++h) {
        const int ib = f * 32 + q * 8 + h * 4;
#pragma unroll
        for (int r = 0; r < 4; ++r) g_v[bg][ib + r] = vcur[f][h][r];
      }
    if (lane < 16) g_Lb[bg] = L;
  }

  // ===== last-block combine: Z[b] = log(sum_j alpha*v) + Lf + Lb =====
  __threadfence();  // publish this block's boundary data
  int tk = 0;
  if (threadIdx.x == 0) tk = atomicAdd(&g_done, 1);
  tk = __shfl(tk, 0, 64);
  if (tk == 7) {
    __threadfence();     // acquire: other blocks' captures
    const int b = lane;  // 64 lanes = 64 batches
    float s = 0.f;
#pragma unroll 4
    for (int k = 0; k < 32; ++k) {
      const f32x4 a = *(const f32x4*)&g_alpha[b][k * 4];
      const f32x4 v = *(const f32x4*)&g_v[b][k * 4];
      s += a[0] * v[0] + a[1] * v[1] + a[2] * v[2] + a[3] * v[3];
    }
    out[b] = __logf(s) + g_Lf[b] + g_Lb[b];
    if (threadIdx.x == 0) g_done = 0;  // reset for next replay
  }
}

extern "C" void kernel_launch(void* const* d_in, const int* in_sizes, int n_in,
                              void* d_out, int out_size, void* d_ws,
                              size_t ws_size, hipStream_t stream) {
  const float* em = (const float*)d_in[0];
  const int* lens = (const int*)d_in[1];
  const float* trans = (const float*)d_in[2];
  const float* head = (const float*)d_in[3];
  const float* last = (const float*)d_in[4];
  float* out = (float*)d_out;
  uint32_t* ws = (uint32_t*)d_ws;  // 2048*64*128 bf16 = 32 MiB

  eem_prepass<<<8192, 256, 0, stream>>>(em, ws);
  crf_chain_kernel<<<8, 64, 0, stream>>>(em, lens, trans, head, last, ws, out);
}

// Round 8
// 429.609 us; speedup vs baseline: 1.6771x; 1.6771x over previous
//
#include <hip/hip_runtime.h>
#include <stdint.h>

#define T_LEN 2048
#define B_TOT 64
#define N_TAG 128
#define MID 1024  // fwd applies M_1..M_{MID-1}; bwd applies M'_{MID}..M'_{T-1}

typedef __attribute__((ext_vector_type(4))) float f32x4;
typedef __attribute__((ext_vector_type(8))) short bf16x8;
typedef __attribute__((ext_vector_type(4))) uint32_t u32x4;

template <int S>
struct IC {
  static constexpr int value = S;
};

// boundary handoff (written by scan blocks, combined by the last block to
// finish via device-scope ticket; __threadfence gives cross-XCD visibility)
__device__ __align__(16) float g_alpha[B_TOT][N_TAG];
__device__ __align__(16) float g_v[B_TOT][N_TAG];
__device__ float g_Lf[B_TOT];
__device__ float g_Lb[B_TOT];
__device__ int g_done = 0;

// pack two fp32 -> dword of two bf16 (round-half-up); elem0 in low half
__device__ __forceinline__ uint32_t pack2_bf16(float a, float b) {
  uint32_t ua = __float_as_uint(a) + 0x8000u;
  uint32_t ub = __float_as_uint(b) + 0x8000u;
  return __builtin_amdgcn_perm(ua, ub, 0x03020706u);
}
__device__ __forceinline__ float bf_lo(uint32_t w) {
  return __uint_as_float(w << 16);
}
__device__ __forceinline__ float bf_hi(uint32_t w) {
  return __uint_as_float(w & 0xffff0000u);
}

// prepass: ws[t][b][i] = bf16(exp(em[b][t][i])), i-pairs packed in u32.
// Separate launch (R4: fusing this traffic into the scan poisons the
// latency-critical loop); stream order guarantees visibility to the scan.
__global__ __launch_bounds__(256) void eem_prepass(const float* __restrict__ em,
                                                   uint32_t* __restrict__ ws) {
  const int tid = blockIdx.x * blockDim.x + threadIdx.x;  // 0 .. 2^21-1
  const int b = tid >> 15;
  const int rem = tid & 32767;
  const int t = rem >> 4;
  const int kk = rem & 15;  // 8 floats per thread
  const float4* src =
      (const float4*)(em + ((size_t)b * T_LEN + t) * N_TAG + kk * 8);
  const float4 p0 = src[0];
  const float4 p1 = src[1];
  u32x4 o;
  o[0] = pack2_bf16(__expf(p0.x), __expf(p0.y));
  o[1] = pack2_bf16(__expf(p0.z), __expf(p0.w));
  o[2] = pack2_bf16(__expf(p1.x), __expf(p1.y));
  o[3] = pack2_bf16(__expf(p1.z), __expf(p1.w));
  *(u32x4*)(ws + ((size_t)t * B_TOT + b) * (N_TAG / 2) + kk * 4) = o;
}

// R8: 4 blocks x 512 threads; block b = batch group b, TWO 4-wave clusters:
//   waves 0-3 = fwd chain (t=1..1023 maskless + 1 dummy step), waves 4-7 =
//   bwd chain (t=2047..1024, per-lane identity select for t >= len).
// One wave per SIMD per cluster -> every SIMD carries 1 fwd + 1 bwd wave =
// 2 independent instruction streams (R1's load-bearing hiding), while each
// wave owns a FULL fragment (32 j's, 2 m-tiles, 8 MFMAs as 4 indep 2-chains;
// >=4 waves/group keeps the 32 MFMAs/group spread over 4 SIMDs -- R6's
// fatal miss). Own B-fragment stays in registers (D output IS next step's
// B-fragment), so per step: 3 foreign ds_read_b128 + 1 ds_write_b128.
// A-fragments rotation-baked at init (static indexing, rule-20 safe).
// Both clusters execute exactly 1024 barriers. Combine fused via ticket.
__global__ __launch_bounds__(512, 2) void crf_scan_kernel(
    const float* __restrict__ em, const int* __restrict__ lens,
    const float* __restrict__ trans, const float* __restrict__ head,
    const float* __restrict__ last, const uint32_t* __restrict__ eem,
    float* __restrict__ out) {
  const int lane = threadIdx.x & 63;
  const int w = threadIdx.x >> 6;  // 0..7
  const int fw = w & 3;            // owned fragment
  const int cl = w >> 2;           // 0 = fwd cluster, 1 = bwd cluster
  const int c = lane & 15;         // batch-in-group
  const int q = lane >> 4;         // 0..3
  const int bg = (int)blockIdx.x * 16 + c;
  const int jb = fw * 32 + q * 8;  // lane's 8 state indices

  __shared__ uint32_t x_lds[2][2][4][64][4];  // [pp][cluster][frag][lane][dw]
  __shared__ int k_lds[2][16];
  __shared__ int ticket_lds;

  // per-lane emission pointer: 8 bf16 (u32x4) of a row for this lane's 8 j's
  const uint32_t* eqp = eem + (size_t)bg * 64 + fw * 16 + q * 4;
  const float* emb = em + (size_t)bg * T_LEN * N_TAG;

  u32x4 eslot[8];
  auto issue_eem = [&](auto sc, int row) {
    constexpr int S = decltype(sc)::value;
    eslot[S] = *(const u32x4*)(eqp + (size_t)row * 4096);
  };
  const f32x4 vzero = {0.f, 0.f, 0.f, 0.f};

  // A fragments, ROTATION-BAKED: efrag[mt][ktv] holds k-tile (fw+ktv)&3,
  // so all MFMA operand indices are compile-time constants.
  bf16x8 efrag[2][4];
  if (cl == 0) {
    // fwd: A[m][k=i] = exp(trans[i][j(m)]), j(m) = fw*32+(c>>2)*8+mt*4+(c&3)
#pragma unroll
    for (int mt = 0; mt < 2; ++mt) {
      const int j = fw * 32 + (c >> 2) * 8 + mt * 4 + (c & 3);
#pragma unroll
      for (int ktv = 0; ktv < 4; ++ktv) {
        const int ktp = (fw + ktv) & 3;
        u32x4 wd;
#pragma unroll
        for (int p = 0; p < 4; ++p) {
          const int i0 = ktp * 32 + q * 8 + 2 * p;
          wd[p] = pack2_bf16(__expf(trans[(i0 + 0) * N_TAG + j]),
                             __expf(trans[(i0 + 1) * N_TAG + j]));
        }
        efrag[mt][ktv] = __builtin_bit_cast(bf16x8, wd);
      }
    }
  } else {
    // bwd: A[m][k=j'] = exp(trans[i(m)][j']), i(m) = fw*32+(c>>2)*8+mt*4+(c&3)
#pragma unroll
    for (int mt = 0; mt < 2; ++mt) {
      const int irow = fw * 32 + (c >> 2) * 8 + mt * 4 + (c & 3);
#pragma unroll
      for (int ktv = 0; ktv < 4; ++ktv) {
        const int ktp = (fw + ktv) & 3;
        u32x4 wd;
#pragma unroll
        for (int p = 0; p < 4; ++p) {
          const int j0 = ktp * 32 + q * 8 + 2 * p;
          wd[p] = pack2_bf16(__expf(trans[irow * N_TAG + j0 + 0]),
                             __expf(trans[irow * N_TAG + j0 + 1]));
        }
        efrag[mt][ktv] = __builtin_bit_cast(bf16x8, wd);
      }
    }
  }

  u32x4 xreg;  // own packed fragment (register copy of this wave's LDS slot)
  float L = 0.f;
  float vprev[8];  // bwd-only f32 state
  const int mylen = (cl == 1) ? lens[bg] : 0;

  if (cl == 0) {
    float v0[8];
#pragma unroll
    for (int r = 0; r < 8; ++r) v0[r] = __expf(head[jb + r] + emb[jb + r]);
#pragma unroll
    for (int d = 0; d < 4; ++d) xreg[d] = pack2_bf16(v0[2 * d], v0[2 * d + 1]);
    if (w == 0 && lane < 16) k_lds[0][lane] = 0;
  } else {
#pragma unroll
    for (int r = 0; r < 8; ++r) vprev[r] = __expf(last[jb + r]);
    const u32x4 e0 = *(const u32x4*)(eqp + (size_t)(T_LEN - 1) * 4096);
#pragma unroll
    for (int d = 0; d < 4; ++d)
      xreg[d] = pack2_bf16(vprev[2 * d] * bf_lo(e0[d]),
                           vprev[2 * d + 1] * bf_hi(e0[d]));
    if (w == 4 && lane < 16) k_lds[1][lane] = 0;
  }
  *(u32x4*)&x_lds[0][cl][fw][lane][0] = xreg;
  __syncthreads();

  if (cl == 0) {
    // ================= forward cluster =================
    issue_eem(IC<1>{}, 1);
    issue_eem(IC<2>{}, 2);
    issue_eem(IC<3>{}, 3);
    issue_eem(IC<4>{}, 4);
    issue_eem(IC<5>{}, 5);
    issue_eem(IC<6>{}, 6);
    issue_eem(IC<7>{}, 7);

    auto stepf = [&](auto sc_, int t) {
      constexpr int SLOT = decltype(sc_)::value;
      constexpr int RP = (SLOT + 1) & 1;
      constexpr int WP = SLOT & 1;
      issue_eem(IC<(SLOT + 7) & 7>{}, t + 7);  // max row 1031 < 2048
      int e = 0;
      if ((SLOT & 3) == 1) e = k_lds[0][c];
      // 3 foreign fragments (own = xreg)
      const u32x4 b1 = *(const u32x4*)&x_lds[RP][0][(fw + 1) & 3][lane][0];
      const u32x4 b2 = *(const u32x4*)&x_lds[RP][0][(fw + 2) & 3][lane][0];
      const u32x4 b3 = *(const u32x4*)&x_lds[RP][0][(fw + 3) & 3][lane][0];
      const u32x4 ev = eslot[SLOT];
      float ff[8];
#pragma unroll
      for (int d = 0; d < 4; ++d) {
        ff[2 * d] = bf_lo(ev[d]);
        ff[2 * d + 1] = bf_hi(ev[d]);
      }
      if ((SLOT & 3) == 1) {
        const float sc = __uint_as_float((uint32_t)(127 - e) << 23);
#pragma unroll
        for (int r = 0; r < 8; ++r) ff[r] *= sc;
        L += (float)e * 0.6931471805599453f;
      }
      // 4 independent 2-deep chains; chains x* start on xreg (no LDS dep)
      const bf16x8 bx = __builtin_bit_cast(bf16x8, xreg);
      f32x4 x0 = __builtin_amdgcn_mfma_f32_16x16x32_bf16(efrag[0][0], bx,
                                                         vzero, 0, 0, 0);
      f32x4 x1 = __builtin_amdgcn_mfma_f32_16x16x32_bf16(efrag[1][0], bx,
                                                         vzero, 0, 0, 0);
      f32x4 y0 = __builtin_amdgcn_mfma_f32_16x16x32_bf16(
          efrag[0][2], __builtin_bit_cast(bf16x8, b2), vzero, 0, 0, 0);
      f32x4 y1 = __builtin_amdgcn_mfma_f32_16x16x32_bf16(
          efrag[1][2], __builtin_bit_cast(bf16x8, b2), vzero, 0, 0, 0);
      x0 = __builtin_amdgcn_mfma_f32_16x16x32_bf16(
          efrag[0][1], __builtin_bit_cast(bf16x8, b1), x0, 0, 0, 0);
      x1 = __builtin_amdgcn_mfma_f32_16x16x32_bf16(
          efrag[1][1], __builtin_bit_cast(bf16x8, b1), x1, 0, 0, 0);
      y0 = __builtin_amdgcn_mfma_f32_16x16x32_bf16(
          efrag[0][3], __builtin_bit_cast(bf16x8, b3), y0, 0, 0, 0);
      y1 = __builtin_amdgcn_mfma_f32_16x16x32_bf16(
          efrag[1][3], __builtin_bit_cast(bf16x8, b3), y1, 0, 0, 0);
      const f32x4 a0 = x0 + y0;  // j = jb + 0..3
      const f32x4 a1 = x1 + y1;  // j = jb + 4..7
      if ((SLOT & 3) == 0) {  // exponent probe of alpha[j=0]
        if (w == 0 && lane < 16)
          k_lds[0][c] = (int)(__float_as_uint(a0[0]) >> 23) - 126;
      }
      if (t == MID - 1) {  // mid-boundary capture (f32 precision)
#pragma unroll
        for (int r = 0; r < 4; ++r) {
          g_alpha[bg][jb + r] = a0[r] * ff[r];
          g_alpha[bg][jb + 4 + r] = a1[r] * ff[4 + r];
        }
        if (w == 0 && lane < 16) g_Lf[bg] = L;
      }
      u32x4 wd;
      wd[0] = pack2_bf16(a0[0] * ff[0], a0[1] * ff[1]);
      wd[1] = pack2_bf16(a0[2] * ff[2], a0[3] * ff[3]);
      wd[2] = pack2_bf16(a1[0] * ff[4], a1[1] * ff[5]);
      wd[3] = pack2_bf16(a1[2] * ff[6], a1[3] * ff[7]);
      xreg = wd;
      *(u32x4*)&x_lds[WP][0][fw][lane][0] = wd;
      __syncthreads();
    };

    int t = 1;
#pragma unroll 1
    for (int it = 0; it < 128; ++it) {  // t = 1..1024 (capture@1023, 1 dummy)
      stepf(IC<1>{}, t);
      stepf(IC<2>{}, t + 1);
      stepf(IC<3>{}, t + 2);
      stepf(IC<4>{}, t + 3);
      stepf(IC<5>{}, t + 4);
      stepf(IC<6>{}, t + 5);
      stepf(IC<7>{}, t + 6);
      stepf(IC<0>{}, t + 7);
      t += 8;
    }
  } else {
    // ================= backward cluster =================
    issue_eem(IC<1>{}, T_LEN - 2);  // slot S holds row 2047-S
    issue_eem(IC<2>{}, T_LEN - 3);
    issue_eem(IC<3>{}, T_LEN - 4);
    issue_eem(IC<4>{}, T_LEN - 5);
    issue_eem(IC<5>{}, T_LEN - 6);
    issue_eem(IC<6>{}, T_LEN - 7);
    issue_eem(IC<7>{}, T_LEN - 8);

    auto stepb = [&](auto sc_, int t) {
      constexpr int SLOT = decltype(sc_)::value;
      constexpr int RP = (SLOT + 1) & 1;
      constexpr int WP = SLOT & 1;
      issue_eem(IC<(SLOT + 7) & 7>{}, t - 8);  // min row 1016 >= 0
      int e = 0;
      if ((SLOT & 3) == 1) e = k_lds[1][c];
      const u32x4 b1 = *(const u32x4*)&x_lds[RP][1][(fw + 1) & 3][lane][0];
      const u32x4 b2 = *(const u32x4*)&x_lds[RP][1][(fw + 2) & 3][lane][0];
      const u32x4 b3 = *(const u32x4*)&x_lds[RP][1][(fw + 3) & 3][lane][0];
      const u32x4 ev = eslot[SLOT];  // e_{t-1}, for packing u_{t-1}
      float ee[8];
#pragma unroll
      for (int d = 0; d < 4; ++d) {
        ee[2 * d] = bf_lo(ev[d]);
        ee[2 * d + 1] = bf_hi(ev[d]);
      }
      const bf16x8 bx = __builtin_bit_cast(bf16x8, xreg);
      f32x4 x0 = __builtin_amdgcn_mfma_f32_16x16x32_bf16(efrag[0][0], bx,
                                                         vzero, 0, 0, 0);
      f32x4 x1 = __builtin_amdgcn_mfma_f32_16x16x32_bf16(efrag[1][0], bx,
                                                         vzero, 0, 0, 0);
      f32x4 y0 = __builtin_amdgcn_mfma_f32_16x16x32_bf16(
          efrag[0][2], __builtin_bit_cast(bf16x8, b2), vzero, 0, 0, 0);
      f32x4 y1 = __builtin_amdgcn_mfma_f32_16x16x32_bf16(
          efrag[1][2], __builtin_bit_cast(bf16x8, b2), vzero, 0, 0, 0);
      x0 = __builtin_amdgcn_mfma_f32_16x16x32_bf16(
          efrag[0][1], __builtin_bit_cast(bf16x8, b1), x0, 0, 0, 0);
      x1 = __builtin_amdgcn_mfma_f32_16x16x32_bf16(
          efrag[1][1], __builtin_bit_cast(bf16x8, b1), x1, 0, 0, 0);
      y0 = __builtin_amdgcn_mfma_f32_16x16x32_bf16(
          efrag[0][3], __builtin_bit_cast(bf16x8, b3), y0, 0, 0, 0);
      y1 = __builtin_amdgcn_mfma_f32_16x16x32_bf16(
          efrag[1][3], __builtin_bit_cast(bf16x8, b3), y1, 0, 0, 0);
      const f32x4 a0 = x0 + y0;  // i = jb + 0..3
      const f32x4 a1 = x1 + y1;  // i = jb + 4..7
      // identity select for padded steps (t >= len): keep v unchanged
      const bool valid = (t < mylen);
      float vnew[8];
#pragma unroll
      for (int r = 0; r < 4; ++r) {
        vnew[r] = valid ? a0[r] : vprev[r];
        vnew[4 + r] = valid ? a1[r] : vprev[4 + r];
      }
      if ((SLOT & 3) == 1) {
        const float sc = __uint_as_float((uint32_t)(127 - e) << 23);
#pragma unroll
        for (int r = 0; r < 8; ++r) vnew[r] *= sc;
        L += (float)e * 0.6931471805599453f;
      }
      if ((SLOT & 3) == 0) {
        if (w == 4 && lane < 16)
          k_lds[1][c] = (int)(__float_as_uint(vnew[0]) >> 23) - 126;
      }
      if (t == MID) {  // mid-boundary capture
#pragma unroll
        for (int r = 0; r < 8; ++r) g_v[bg][jb + r] = vnew[r];
        if (w == 4 && lane < 16) g_Lb[bg] = L;
      }
      u32x4 wd;
#pragma unroll
      for (int d = 0; d < 4; ++d)
        wd[d] = pack2_bf16(vnew[2 * d] * ee[2 * d],
                           vnew[2 * d + 1] * ee[2 * d + 1]);
      xreg = wd;
      *(u32x4*)&x_lds[WP][1][fw][lane][0] = wd;
#pragma unroll
      for (int r = 0; r < 8; ++r) vprev[r] = vnew[r];
      __syncthreads();
    };

    int t = T_LEN - 1;  // 2047
#pragma unroll 1
    for (int it = 0; it < 128; ++it) {  // t = 2047..1024 (capture at 1024)
      stepb(IC<1>{}, t);
      stepb(IC<2>{}, t - 1);
      stepb(IC<3>{}, t - 2);
      stepb(IC<4>{}, t - 3);
      stepb(IC<5>{}, t - 4);
      stepb(IC<6>{}, t - 5);
      stepb(IC<7>{}, t - 6);
      stepb(IC<0>{}, t - 7);
      t -= 8;
    }
  }

  // ===== last-block combine: Z[b] = log(sum_j alpha*v) + Lf + Lb =====
  __threadfence();  // publish this block's boundary data
  if (threadIdx.x == 0) ticket_lds = atomicAdd(&g_done, 1);
  __syncthreads();
  if (ticket_lds == 3) {
    __threadfence();  // acquire: other blocks' captures
    const int b = threadIdx.x >> 3;  // 64 batches x 8 threads
    const int p = threadIdx.x & 7;
    float s = 0.f;
#pragma unroll
    for (int k = 0; k < 4; ++k) {
      const f32x4 a = *(const f32x4*)&g_alpha[b][p * 16 + k * 4];
      const f32x4 v = *(const f32x4*)&g_v[b][p * 16 + k * 4];
      s += a[0] * v[0] + a[1] * v[1] + a[2] * v[2] + a[3] * v[3];
    }
    s += __shfl_xor(s, 1);
    s += __shfl_xor(s, 2);
    s += __shfl_xor(s, 4);
    if (p == 0) out[b] = __logf(s) + g_Lf[b] + g_Lb[b];
    __syncthreads();
    if (threadIdx.x == 0) g_done = 0;  // reset for next replay
  }
}

extern "C" void kernel_launch(void* const* d_in, const int* in_sizes, int n_in,
                              void* d_out, int out_size, void* d_ws,
                              size_t ws_size, hipStream_t stream) {
  const float* em = (const float*)d_in[0];
  const int* lens = (const int*)d_in[1];
  const float* trans = (const float*)d_in[2];
  const float* head = (const float*)d_in[3];
  const float* last = (const float*)d_in[4];
  float* out = (float*)d_out;
  uint32_t* ws = (uint32_t*)d_ws;  // 2048*64*128 bf16 = 32 MiB

  eem_prepass<<<8192, 256, 0, stream>>>(em, ws);
  crf_scan_kernel<<<4, 512, 0, stream>>>(em, lens, trans, head, last, ws, out);
}

// Round 9
// 355.640 us; speedup vs baseline: 2.0259x; 1.2080x over previous
//
#include <hip/hip_runtime.h>
#include <stdint.h>

#define T_LEN 2048
#define B_TOT 64
#define N_TAG 128
#define MID 1024  // fwd applies M_1..M_{MID-1}; bwd applies M'_{MID}..M'_{T-1}

typedef __attribute__((ext_vector_type(4))) float f32x4;
typedef __attribute__((ext_vector_type(8))) short bf16x8;
typedef __attribute__((ext_vector_type(4))) uint32_t u32x4;
typedef __attribute__((ext_vector_type(2))) uint32_t u32x2;

template <int S>
struct IC {
  static constexpr int value = S;
};

// boundary handoff (written by scan blocks, combined by the last block to
// finish via device-scope ticket; __threadfence gives cross-XCD visibility)
__device__ __align__(16) float g_alpha[B_TOT][N_TAG];
__device__ __align__(16) float g_v[B_TOT][N_TAG];
__device__ float g_Lf[B_TOT];
__device__ float g_Lb[B_TOT];
__device__ int g_done = 0;

// pack two fp32 -> dword of two bf16 (round-half-up); elem0 in low half
__device__ __forceinline__ uint32_t pack2_bf16(float a, float b) {
  uint32_t ua = __float_as_uint(a) + 0x8000u;
  uint32_t ub = __float_as_uint(b) + 0x8000u;
  return __builtin_amdgcn_perm(ua, ub, 0x03020706u);
}
__device__ __forceinline__ float bf_lo(uint32_t w) {
  return __uint_as_float(w << 16);
}
__device__ __forceinline__ float bf_hi(uint32_t w) {
  return __uint_as_float(w & 0xffff0000u);
}

// Raw per-step barrier: orders the LDS state exchange (lgkmcnt only) but
// leaves global (eem prefetch) loads IN FLIGHT across the barrier --
// __syncthreads would emit s_waitcnt vmcnt(0) and drain the ring every step
// (the hidden ~100-150 cyc/step cost in the R1 structure). Pattern is the
// m201-verified sched_barrier/waitcnt/s_barrier sandwich (rule #18: asm
// waitcnt must be fenced by sched_barrier(0)).
__device__ __forceinline__ void step_barrier() {
  __builtin_amdgcn_sched_barrier(0);
  asm volatile("s_waitcnt lgkmcnt(0)");
  __builtin_amdgcn_sched_barrier(0);
  __builtin_amdgcn_s_barrier();
  __builtin_amdgcn_sched_barrier(0);
}

// prepass: ws[t][b][i] = bf16(exp(em[b][t][i])), i-pairs packed in u32.
// Separate launch (R4: fusing this traffic into the scan poisons the
// latency-critical loop); stream order guarantees visibility to the scan.
__global__ __launch_bounds__(256) void eem_prepass(const float* __restrict__ em,
                                                   uint32_t* __restrict__ ws) {
  const int tid = blockIdx.x * blockDim.x + threadIdx.x;  // 0 .. 2^21-1
  const int b = tid >> 15;
  const int rem = tid & 32767;
  const int t = rem >> 4;
  const int kk = rem & 15;  // 8 floats per thread
  const float4* src =
      (const float4*)(em + ((size_t)b * T_LEN + t) * N_TAG + kk * 8);
  const float4 p0 = src[0];
  const float4 p1 = src[1];
  u32x4 o;
  o[0] = pack2_bf16(__expf(p0.x), __expf(p0.y));
  o[1] = pack2_bf16(__expf(p0.z), __expf(p0.w));
  o[2] = pack2_bf16(__expf(p1.x), __expf(p1.y));
  o[3] = pack2_bf16(__expf(p1.z), __expf(p1.w));
  *(u32x4*)(ws + ((size_t)t * B_TOT + b) * (N_TAG / 2) + kk * 4) = o;
}

// R9 = R1's verified 227us two-ended 8-wave structure (blocks 0-3 fwd
// t=1..1023 maskless; blocks 4-7 bwd t=2047..1024 with identity select),
// with three surgical changes:
//   (1) step barrier = lgkmcnt-only raw barrier (eem loads span barriers),
//   (2) MFMA 4-chain split into two parallel 2-chains + f32x4 add,
//   (3) combine fused via last-block ticket (one launch fewer).
// Wave w owns 16 j's (fragment f=w>>1, half h=w&1); A rows permuted so the
// f32x4 D output IS the half-fragment of next step's B operand:
// 1 ds_write_b64 + 4 ds_read_b128 per wave per step; 2 waves/SIMD give two
// independent instruction streams (load-bearing, R5/R8 evidence).
__global__ __launch_bounds__(512, 2) void crf_scan_kernel(
    const float* __restrict__ em, const int* __restrict__ lens,
    const float* __restrict__ trans, const float* __restrict__ head,
    const float* __restrict__ last, const uint32_t* __restrict__ eem,
    float* __restrict__ out) {
  const int lane = threadIdx.x & 63;
  const int w = threadIdx.x >> 6;  // 0..7
  const int f = w >> 1;            // owned fragment
  const int h = w & 1;             // half within fragment
  const int c = lane & 15;         // batch-in-tile
  const int q = lane >> 4;
  const bool is_fwd = (blockIdx.x < 4);
  const int bg = ((int)blockIdx.x & 3) * 16 + c;
  const int jbase = f * 32 + q * 8 + h * 4;  // lane's 4 state indices

  __shared__ uint32_t x_lds[2][4][64][4];  // [pingpong][frag][lane][dword]
  __shared__ int k_lds[16];
  __shared__ int ticket_lds;

  const size_t eoff = (size_t)bg * 64 + f * 16 + q * 4 + h * 2;
  u32x2 eslot[4];
  auto issue_eem = [&](auto sc, int row) {
    constexpr int S = decltype(sc)::value;
    eslot[S] = *(const u32x2*)(eem + (size_t)row * 4096 + eoff);
  };

  const f32x4 vzero = {0.f, 0.f, 0.f, 0.f};

  if (is_fwd) {
    // ================= forward half: produce alpha_{MID-1} =================
    // A[m=j][k=i] = exp(trans[i][j]), rows permuted per wave
    bf16x8 efrag[4];
    {
      const int j = f * 32 + (c >> 2) * 8 + h * 4 + (c & 3);
#pragma unroll
      for (int ktv = 0; ktv < 4; ++ktv) {
        const int ktp = (w + ktv) & 3;
        u32x4 wd;
#pragma unroll
        for (int p = 0; p < 4; ++p) {
          const int i0 = ktp * 32 + q * 8 + 2 * p;
          wd[p] = pack2_bf16(__expf(trans[(i0 + 0) * N_TAG + j]),
                             __expf(trans[(i0 + 1) * N_TAG + j]));
        }
        efrag[ktv] = __builtin_bit_cast(bf16x8, wd);
      }
    }
    float L = 0.f;
    const float* emb = em + (size_t)bg * T_LEN * N_TAG;
    {
      float v0[4];
#pragma unroll
      for (int r = 0; r < 4; ++r)
        v0[r] = __expf(head[jbase + r] + emb[jbase + r]);
      u32x2 wd;
      wd[0] = pack2_bf16(v0[0], v0[1]);
      wd[1] = pack2_bf16(v0[2], v0[3]);
      *(u32x2*)&x_lds[0][f][lane][h * 2] = wd;
    }
    if (w == 0 && lane < 16) k_lds[lane] = 0;
    __syncthreads();

    issue_eem(IC<1>{}, 1);
    issue_eem(IC<2>{}, 2);
    issue_eem(IC<3>{}, 3);

    auto step = [&](auto slotc, int t) {
      constexpr int SLOT = decltype(slotc)::value;
      constexpr int RP = (SLOT + 1) & 1;  // read buffer (state of t-1)
      constexpr int WP = SLOT & 1;        // write buffer
      {
        int row = t + 3;
        if (row > T_LEN - 1) row = T_LEN - 1;
        issue_eem(IC<(SLOT + 3) & 3>{}, row);
      }
      int e = 0;
      if (SLOT == 1) e = k_lds[c];
      u32x4 bfr[4];
#pragma unroll
      for (int ktv = 0; ktv < 4; ++ktv)
        bfr[ktv] = *(const u32x4*)&x_lds[RP][(w + ktv) & 3][lane][0];
      const u32x2 ev = eslot[SLOT];
      float ff[4];
      ff[0] = bf_lo(ev[0]);
      ff[1] = bf_hi(ev[0]);
      ff[2] = bf_lo(ev[1]);
      ff[3] = bf_hi(ev[1]);
      if (SLOT == 1) {
        const float sc = __uint_as_float((uint32_t)(127 - e) << 23);
#pragma unroll
        for (int r = 0; r < 4; ++r) ff[r] *= sc;
        L += (float)e * 0.6931471805599453f;
      }
      // two parallel 2-deep MFMA chains + one add (same sum, half dep depth)
      f32x4 a0 = __builtin_amdgcn_mfma_f32_16x16x32_bf16(
          efrag[0], __builtin_bit_cast(bf16x8, bfr[0]), vzero, 0, 0, 0);
      f32x4 a1 = __builtin_amdgcn_mfma_f32_16x16x32_bf16(
          efrag[2], __builtin_bit_cast(bf16x8, bfr[2]), vzero, 0, 0, 0);
      a0 = __builtin_amdgcn_mfma_f32_16x16x32_bf16(
          efrag[1], __builtin_bit_cast(bf16x8, bfr[1]), a0, 0, 0, 0);
      a1 = __builtin_amdgcn_mfma_f32_16x16x32_bf16(
          efrag[3], __builtin_bit_cast(bf16x8, bfr[3]), a1, 0, 0, 0);
      const f32x4 acc = a0 + a1;
      if (SLOT == 0) {
        // exponent probe of j=0: wave 0, lanes 0-15 hold alpha[0][c]
        if (w == 0 && lane < 16)
          k_lds[c] = (int)(__float_as_uint(acc[0]) >> 23) - 126;
      }
      if (t == MID - 1) {  // mid-boundary capture (full f32 precision)
#pragma unroll
        for (int r = 0; r < 4; ++r) g_alpha[bg][jbase + r] = acc[r] * ff[r];
        if (w == 0 && q == 0) g_Lf[bg] = L;
      }
      u32x2 wd;
      wd[0] = pack2_bf16(acc[0] * ff[0], acc[1] * ff[1]);
      wd[1] = pack2_bf16(acc[2] * ff[2], acc[3] * ff[3]);
      *(u32x2*)&x_lds[WP][f][lane][h * 2] = wd;
      step_barrier();
    };

    int t = 1;
#pragma unroll 1
    for (int it = 0; it < 255; ++it) {  // t = 1 .. 1020
      step(IC<1>{}, t);
      step(IC<2>{}, t + 1);
      step(IC<3>{}, t + 2);
      step(IC<0>{}, t + 3);
      t += 4;
    }
    step(IC<1>{}, t);      // 1021
    step(IC<2>{}, t + 1);  // 1022
    step(IC<3>{}, t + 2);  // 1023 (capture)
  } else {
    // ================= backward half: produce v_MID =================
    // A[m=i][k=j] = exp(trans[i][j]) (untransposed), same row permutation
    bf16x8 efrag[4];
    {
      const int irow = f * 32 + (c >> 2) * 8 + h * 4 + (c & 3);
#pragma unroll
      for (int ktv = 0; ktv < 4; ++ktv) {
        const int ktp = (w + ktv) & 3;
        u32x4 wd;
#pragma unroll
        for (int p = 0; p < 4; ++p) {
          const int j0 = ktp * 32 + q * 8 + 2 * p;
          wd[p] = pack2_bf16(__expf(trans[irow * N_TAG + j0 + 0]),
                             __expf(trans[irow * N_TAG + j0 + 1]));
        }
        efrag[ktv] = __builtin_bit_cast(bf16x8, wd);
      }
    }
    const int mylen = lens[bg];
    float L = 0.f;
    float vprev[4];
    {
      // v_T = exp(last); LDS gets u_{T-1} = e_{T-1} (*) v_T
      const u32x2 ev0 =
          *(const u32x2*)(eem + (size_t)(T_LEN - 1) * 4096 + eoff);
#pragma unroll
      for (int r = 0; r < 4; ++r) vprev[r] = __expf(last[jbase + r]);
      u32x2 wd;
      wd[0] = pack2_bf16(vprev[0] * bf_lo(ev0[0]), vprev[1] * bf_hi(ev0[0]));
      wd[1] = pack2_bf16(vprev[2] * bf_lo(ev0[1]), vprev[3] * bf_hi(ev0[1]));
      *(u32x2*)&x_lds[0][f][lane][h * 2] = wd;
    }
    if (w == 0 && lane < 16) k_lds[lane] = 0;
    __syncthreads();

    issue_eem(IC<1>{}, T_LEN - 2);  // e_{t-1} for t = 2047
    issue_eem(IC<2>{}, T_LEN - 3);
    issue_eem(IC<3>{}, T_LEN - 4);

    auto step = [&](auto slotc, int t) {
      constexpr int SLOT = decltype(slotc)::value;
      constexpr int RP = (SLOT + 1) & 1;
      constexpr int WP = SLOT & 1;
      {
        int row = t - 4;
        if (row < 0) row = 0;
        issue_eem(IC<(SLOT + 3) & 3>{}, row);
      }
      int e = 0;
      if (SLOT == 1) e = k_lds[c];
      u32x4 bfr[4];
#pragma unroll
      for (int ktv = 0; ktv < 4; ++ktv)
        bfr[ktv] = *(const u32x4*)&x_lds[RP][(w + ktv) & 3][lane][0];
      const u32x2 ev = eslot[SLOT];  // e_{t-1}, for packing u_{t-1}
      float ee[4];
      ee[0] = bf_lo(ev[0]);
      ee[1] = bf_hi(ev[0]);
      ee[2] = bf_lo(ev[1]);
      ee[3] = bf_hi(ev[1]);
      f32x4 a0 = __builtin_amdgcn_mfma_f32_16x16x32_bf16(
          efrag[0], __builtin_bit_cast(bf16x8, bfr[0]), vzero, 0, 0, 0);
      f32x4 a1 = __builtin_amdgcn_mfma_f32_16x16x32_bf16(
          efrag[2], __builtin_bit_cast(bf16x8, bfr[2]), vzero, 0, 0, 0);
      a0 = __builtin_amdgcn_mfma_f32_16x16x32_bf16(
          efrag[1], __builtin_bit_cast(bf16x8, bfr[1]), a0, 0, 0, 0);
      a1 = __builtin_amdgcn_mfma_f32_16x16x32_bf16(
          efrag[3], __builtin_bit_cast(bf16x8, bfr[3]), a1, 0, 0, 0);
      const f32x4 acc = a0 + a1;
      // identity select for padded steps (t >= len): keep v unchanged
      const bool valid = (t < mylen);
      float vnew[4];
#pragma unroll
      for (int r = 0; r < 4; ++r) vnew[r] = valid ? acc[r] : vprev[r];
      if (SLOT == 1) {
        const float sc = __uint_as_float((uint32_t)(127 - e) << 23);
#pragma unroll
        for (int r = 0; r < 4; ++r) vnew[r] *= sc;
        L += (float)e * 0.6931471805599453f;
      }
      if (SLOT == 0) {
        if (w == 0 && lane < 16)
          k_lds[c] = (int)(__float_as_uint(vnew[0]) >> 23) - 126;
      }
      if (t == MID) {  // mid-boundary capture
#pragma unroll
        for (int r = 0; r < 4; ++r) g_v[bg][jbase + r] = vnew[r];
        if (w == 0 && q == 0) g_Lb[bg] = L;
      }
      u32x2 wd;
      wd[0] = pack2_bf16(vnew[0] * ee[0], vnew[1] * ee[1]);
      wd[1] = pack2_bf16(vnew[2] * ee[2], vnew[3] * ee[3]);
      *(u32x2*)&x_lds[WP][f][lane][h * 2] = wd;
#pragma unroll
      for (int r = 0; r < 4; ++r) vprev[r] = vnew[r];
      step_barrier();
    };

    int t = T_LEN - 1;  // 2047
#pragma unroll 1
    for (int it = 0; it < 256; ++it) {  // t = 2047 .. 1024 (capture at 1024)
      step(IC<1>{}, t);
      step(IC<2>{}, t - 1);
      step(IC<3>{}, t - 2);
      step(IC<0>{}, t - 3);
      t -= 4;
    }
  }

  // ===== last-block combine: Z[b] = log(sum_j alpha*v) + Lf + Lb =====
  __threadfence();  // publish this block's g_alpha / g_v / g_Lf / g_Lb
  if (threadIdx.x == 0) ticket_lds = atomicAdd(&g_done, 1);
  __syncthreads();
  if (ticket_lds == 7) {
    __threadfence();  // acquire: other blocks' captures
    const int b = threadIdx.x >> 3;  // 64 batches x 8 threads
    const int p = threadIdx.x & 7;
    float s = 0.f;
#pragma unroll
    for (int k = 0; k < 4; ++k) {
      const f32x4 a = *(const f32x4*)&g_alpha[b][p * 16 + k * 4];
      const f32x4 v = *(const f32x4*)&g_v[b][p * 16 + k * 4];
      s += a[0] * v[0] + a[1] * v[1] + a[2] * v[2] + a[3] * v[3];
    }
    s += __shfl_xor(s, 1);
    s += __shfl_xor(s, 2);
    s += __shfl_xor(s, 4);
    if (p == 0) out[b] = __logf(s) + g_Lf[b] + g_Lb[b];
    __syncthreads();
    if (threadIdx.x == 0) g_done = 0;  // reset for next replay
  }
}

extern "C" void kernel_launch(void* const* d_in, const int* in_sizes, int n_in,
                              void* d_out, int out_size, void* d_ws,
                              size_t ws_size, hipStream_t stream) {
  const float* em = (const float*)d_in[0];
  const int* lens = (const int*)d_in[1];
  const float* trans = (const float*)d_in[2];
  const float* head = (const float*)d_in[3];
  const float* last = (const float*)d_in[4];
  float* out = (float*)d_out;
  uint32_t* ws = (uint32_t*)d_ws;  // 2048*64*128 bf16 = 32 MiB

  eem_prepass<<<8192, 256, 0, stream>>>(em, ws);
  crf_scan_kernel<<<8, 512, 0, stream>>>(em, lens, trans, head, last, ws, out);
}